// Round 18
// baseline (129.060 us; speedup 1.0000x reference)
//
#include <hip/hip_runtime.h>
#include <hip/hip_bf16.h>
#include <stdint.h>

// Problem constants
#define B_ 32
#define L_ 512
#define I_ 1024
#define O_ 1024
#define NST 32            // K-steps of BK=32

typedef float  f32x4 __attribute__((ext_vector_type(4)));
typedef __bf16 bf16x4 __attribute__((ext_vector_type(4)));
typedef __bf16 bf16x8 __attribute__((ext_vector_type(8)));

#define CFENCE() asm volatile("" ::: "memory")
#define BARRIER() do { CFENCE(); __builtin_amdgcn_s_barrier(); CFENCE(); } while (0)
#define LGKM0()  asm volatile("s_waitcnt lgkmcnt(0)" ::: "memory")

// ---- async global->LDS, 16B per lane ----
__device__ __forceinline__ void gload_lds16(const void* g, void* l) {
    __builtin_amdgcn_global_load_lds(
        (const __attribute__((address_space(1))) uint32_t*)(uintptr_t)g,
        (__attribute__((address_space(3))) uint32_t*)(uint32_t)(uintptr_t)l,
        16, 0, 0);
}

// ============================ Pass 0: mean,logvar f32 -> mean bf16, sigma bf16 (4 MiB) ============================
__global__ void gen_ms_kernel(const float* __restrict__ wmean, const float* __restrict__ wlv,
                              __bf16* __restrict__ mz, __bf16* __restrict__ sgm)
{
    const int i = blockIdx.x * blockDim.x + threadIdx.x;   // exactly O*I/4 threads
    const f32x4 m = *(const f32x4*)(wmean + (size_t)i * 4);
    const f32x4 l = *(const f32x4*)(wlv   + (size_t)i * 4);
    bf16x4 mb, sb;
    #pragma unroll
    for (int e = 0; e < 4; ++e) {
        mb[e] = (__bf16)m[e];
        sb[e] = (__bf16)__expf(0.5f * l[e]);
    }
    *(bf16x4*)(mz  + (size_t)i * 4) = mb;
    *(bf16x4*)(sgm + (size_t)i * 4) = sb;
}

// ============================ Fused GEMM: A(f32) via gload_lds, B(W) reg-built ============================
// C[b](512x1024) = X[b] * (mean + noise[b]*sigma)^T + bias.  Tile 128(M) x 256(N), BK=32.
// 512 thr = 8 waves (2M x 4N), per-wave 64x64 out = 4x4 frags -> acc 64 regs.
// A side: x staged as RAW F32 via gload_lds (ZERO staging regs, no cvt_x pass); f32->bf16
// conversion happens at fragment load (2x ds_read_b128 + cvt per frag).
// B side: reg-staged transform W = mean + noise*sigma (8 loads, 32 regs — half of R13's,
// which is the variant hipcc register-starved).
// LDS 64 KB: 2 dbuf x { A f32 128x32 (16KB, src-swizzled chunk^=(row&7), rule-21 form) |
//                       B bf16 256x32 (16KB, write-swizzled chunk^=( (row>>1)&3 )) }.
// Both frag-read patterns enumerate to uniform 8 lanes/bank-quad = b128 optimum.
// Sync: R5/R13-proven 2-phase full-drain (__syncthreads per step) — no hand vmcnt.
__global__ __launch_bounds__(512, 2) void fused_a(const float* __restrict__ x,
                                                  const float* __restrict__ noise,
                                                  const __bf16* __restrict__ mz,
                                                  const __bf16* __restrict__ sgm,
                                                  const float* __restrict__ bias,
                                                  float* __restrict__ out)
{
    __shared__ __align__(16) char smem[65536];   // buf d at d*32768: A@0 (16KB), B@16384 (16KB)

    // 512 blocks, XCD swizzle (512%8==0): 64 consecutive logical blocks per XCD = 4 whole batches.
    const int bid = ((int)blockIdx.x & 7) * 64 + ((int)blockIdx.x >> 3);
    const int b   = bid >> 4;          // 16 blocks/batch
    const int mt  = (bid >> 2) & 3;    // 4 M-tiles of 128
    const int nt  = bid & 3;           // 4 N-tiles of 256

    const int tid  = threadIdx.x;      // 0..511
    const int wid  = tid >> 6, lane = tid & 63;
    const int wr   = wid >> 2;         // 0..1 (M halves of 64)
    const int wc   = wid & 3;          // 0..3 (N quarters of 64)
    const int hr   = lane & 15;
    const int kq   = lane >> 4;        // 0..3

    // ---- A staging (gload, f32): thread owns phys chunks tid (row rA) and tid+512 (row rA+64) ----
    // phys chunk p: row p>>3 (8 chunks/row), pc p&7; logical col chunk c = pc ^ (row&7)
    const int rA = tid >> 3, pcA = tid & 7;
    const int cA = pcA ^ (rA & 7);                // same for row+64
    const float* xg1 = x + ((size_t)b * L_ + mt * 128 + rA) * I_ + cA * 4;
    const float* xg2 = xg1 + (size_t)64 * I_;

#define STG_A(k0_, d_) do {                                            \
        char* ab_ = smem + (d_) * 32768;                               \
        gload_lds16(xg1 + (k0_), ab_ + tid * 16);                      \
        gload_lds16(xg2 + (k0_), ab_ + 8192 + tid * 16);               \
    } while (0)

    // ---- B staging (regs): thread owns chunks (rB,cB) and (rB+128,cB); 4 chunks/row ----
    const int rB = tid >> 2, pcB = tid & 3;
    const int cB = pcB ^ ((rB >> 1) & 3);         // same for row+128
    const float*  ng1 = noise + ((size_t)b * O_ + nt * 256 + rB) * I_ + cB * 8;
    const float*  ng2 = ng1 + (size_t)128 * I_;
    const __bf16* mg1 = mz  + (size_t)(nt * 256 + rB) * I_ + cB * 8;
    const __bf16* mg2 = mg1 + (size_t)128 * I_;
    const __bf16* gg1 = sgm + (size_t)(nt * 256 + rB) * I_ + cB * 8;
    const __bf16* gg2 = gg1 + (size_t)128 * I_;
    const int wbB = 16384 + rB * 64 + pcB * 16;   // phys write byte; chunk2 = +8192

    f32x4 sn0, sn1, sn2, sn3; bf16x8 sm0, sm1, sg0, sg1;

#define B_ISSUE(k0_) do {                                              \
        sn0 = *(const f32x4*)(ng1 + (k0_));                            \
        sn1 = *(const f32x4*)(ng1 + (k0_) + 4);                        \
        sn2 = *(const f32x4*)(ng2 + (k0_));                            \
        sn3 = *(const f32x4*)(ng2 + (k0_) + 4);                        \
        sm0 = *(const bf16x8*)(mg1 + (k0_));                           \
        sm1 = *(const bf16x8*)(mg2 + (k0_));                           \
        sg0 = *(const bf16x8*)(gg1 + (k0_));                           \
        sg1 = *(const bf16x8*)(gg2 + (k0_));                           \
    } while (0)

#define B_WRITE(d_) do {                                                     \
        bf16x8 w0_, w1_;                                                     \
        _Pragma("unroll")                                                    \
        for (int e = 0; e < 4; ++e) {                                        \
            w0_[e]   = (__bf16)((float)sm0[e]   + sn0[e] * (float)sg0[e]);   \
            w0_[e+4] = (__bf16)((float)sm0[e+4] + sn1[e] * (float)sg0[e+4]); \
            w1_[e]   = (__bf16)((float)sm1[e]   + sn2[e] * (float)sg1[e]);   \
            w1_[e+4] = (__bf16)((float)sm1[e+4] + sn3[e] * (float)sg1[e+4]); \
        }                                                                    \
        *(bf16x8*)(smem + (d_) * 32768 + wbB)        = w0_;                  \
        *(bf16x8*)(smem + (d_) * 32768 + wbB + 8192) = w1_;                  \
    } while (0)

    // ---- frag read offsets ----
    // A: row = wr*64 + f*16 + hr (f32 rows of 128B); chunks (kq*2+j) ^ (hr&7)
    int aoff[4][2];
    #pragma unroll
    for (int f = 0; f < 4; ++f)
        #pragma unroll
        for (int j = 0; j < 2; ++j)
            aoff[f][j] = (wr * 64 + f * 16 + hr) * 128 + (((kq * 2 + j) ^ (hr & 7)) * 16);
    // B: rowB = wc*64 + n*16 + hr (bf16 rows of 64B); chunk kq ^ ((hr>>1)&3)
    int boff[4];
    #pragma unroll
    for (int n = 0; n < 4; ++n)
        boff[n] = 16384 + (wc * 64 + n * 16 + hr) * 64 + ((kq ^ ((hr >> 1) & 3)) * 16);

    f32x4 acc[4][4];
    #pragma unroll
    for (int m = 0; m < 4; ++m)
        #pragma unroll
        for (int n = 0; n < 4; ++n)
            acc[m][n] = (f32x4)(0.0f);

    // ---- prologue: build tile 0 into buf 0; issue B(1) ----
    STG_A(0, 0);
    B_ISSUE(0);
    B_WRITE(0);            // compiler waits the B loads
    B_ISSUE(32);           // tile 1 B regs
    LGKM0();
    __syncthreads();       // drains A gloads (vmcnt0) + publishes B writes

    for (int t = 0; t < NST; ++t) {
        const char* base = smem + (t & 1) * 32768;

        // issue next tile's A (gload into other buf) BEFORE compute
        if (t + 1 < NST) STG_A((t + 1) * 32, (t + 1) & 1);

        // A frags: 2x ds_read_b128 f32 -> cvt to bf16x8
        bf16x8 af[4], bfr[4];
        #pragma unroll
        for (int f = 0; f < 4; ++f) {
            const f32x4 lo = *(const f32x4*)(base + aoff[f][0]);
            const f32x4 hi = *(const f32x4*)(base + aoff[f][1]);
            bf16x8 a_;
            #pragma unroll
            for (int e = 0; e < 4; ++e) { a_[e] = (__bf16)lo[e]; a_[e+4] = (__bf16)hi[e]; }
            af[f] = a_;
        }
        #pragma unroll
        for (int n = 0; n < 4; ++n)
            bfr[n] = *(const bf16x8*)(base + boff[n]);

        __builtin_amdgcn_s_setprio(1);
        #pragma unroll
        for (int m = 0; m < 4; ++m)
            #pragma unroll
            for (int n = 0; n < 4; ++n)
                acc[m][n] = __builtin_amdgcn_mfma_f32_16x16x32_bf16(af[m], bfr[n], acc[m][n], 0, 0, 0);
        __builtin_amdgcn_s_setprio(0);

        // B: write tile t+1 (regs issued last step), issue tile t+2
        if (t + 1 < NST) B_WRITE((t + 1) & 1);
        if (t + 2 < NST) B_ISSUE((t + 2) * 32);
        LGKM0();
        __syncthreads();   // drains A gloads of t+1, publishes B writes of t+1
    }
#undef STG_A
#undef B_ISSUE
#undef B_WRITE

    // ---- epilogue: LDS transpose -> coalesced 1KB-row stores; 4 rounds x 32 rows ----
    {
        float* eb = (float*)smem;                  // [32][260] f32 = 33.3 KB
        const f32x4 bias4 = *(const f32x4*)(bias + nt * 256 + lane * 4);
        float* ob = out + ((size_t)b * L_ + mt * 128) * O_ + nt * 256;
        #pragma unroll
        for (int r = 0; r < 4; ++r) {
            BARRIER();                             // prior LDS use done
            if (wr == (r >> 1)) {
                #pragma unroll
                for (int m2 = 0; m2 < 2; ++m2) {
                    const int mf = (r & 1) * 2 + m2;
                    #pragma unroll
                    for (int n = 0; n < 4; ++n) {
                        const int col = wc * 64 + n * 16 + hr;
                        #pragma unroll
                        for (int j = 0; j < 4; ++j)
                            eb[(m2 * 16 + kq * 4 + j) * 260 + col] = acc[mf][n][j];
                    }
                }
            }
            LGKM0();
            BARRIER();                             // publish slab
            #pragma unroll
            for (int rr = 0; rr < 4; ++rr) {
                const int row = wid * 4 + rr;      // 0..31
                f32x4 v = *(const f32x4*)&eb[row * 260 + lane * 4];
                v += bias4;
                *(f32x4*)&ob[(size_t)(r * 32 + row) * O_ + lane * 4] = v;
            }
        }
    }
}

// ============================ Fallback (no workspace): R1 fused kernel ============================
#define LDSPAD 40
__global__ void bayes_gemm_fused(const float* __restrict__ x,
                                 const float* __restrict__ wmean,
                                 const float* __restrict__ wlogvar,
                                 const float* __restrict__ bias,
                                 const float* __restrict__ noise,
                                 float* __restrict__ out)
{
    __shared__ __bf16 As[128 * LDSPAD];
    __shared__ __bf16 Bs[128 * LDSPAD];
    const int bid  = blockIdx.x;
    const int b    = bid >> 5;
    const int mt   = (bid >> 3) & 3;
    const int nt   = bid & 7;
    const int t    = threadIdx.x;
    const int wave = t >> 6, lane = t & 63;
    const int wr   = wave >> 1, wc = wave & 1;
    const int hr   = lane & 15, kq = lane >> 4;
    const float* xb = x     + (size_t)b * L_ * I_;
    const float* nb = noise + (size_t)b * O_ * I_;
    f32x4 acc[4][4];
    #pragma unroll
    for (int m = 0; m < 4; ++m)
        #pragma unroll
        for (int n = 0; n < 4; ++n) acc[m][n] = (f32x4)(0.0f);
    for (int k0 = 0; k0 < I_; k0 += 32) {
        #pragma unroll
        for (int j = 0; j < 4; ++j) {
            const int s = t + j * 256, row = s >> 3, q = s & 7;
            const float4 v = *(const float4*)(xb + (size_t)(mt * 128 + row) * I_ + k0 + q * 4);
            __bf16* dst = &As[row * LDSPAD + q * 4];
            dst[0] = (__bf16)v.x; dst[1] = (__bf16)v.y; dst[2] = (__bf16)v.z; dst[3] = (__bf16)v.w;
        }
        #pragma unroll
        for (int j = 0; j < 4; ++j) {
            const int s = t + j * 256, row = s >> 3, q = s & 7;
            const size_t off = (size_t)(nt * 128 + row) * I_ + k0 + q * 4;
            const float4 m4 = *(const float4*)(wmean + off);
            const float4 l4 = *(const float4*)(wlogvar + off);
            const float4 n4 = *(const float4*)(nb + off);
            __bf16* dst = &Bs[row * LDSPAD + q * 4];
            dst[0] = (__bf16)(m4.x + n4.x * __expf(0.5f * l4.x));
            dst[1] = (__bf16)(m4.y + n4.y * __expf(0.5f * l4.y));
            dst[2] = (__bf16)(m4.z + n4.z * __expf(0.5f * l4.z));
            dst[3] = (__bf16)(m4.w + n4.w * __expf(0.5f * l4.w));
        }
        __syncthreads();
        bf16x8 af[4], bfr[4];
        #pragma unroll
        for (int m = 0; m < 4; ++m)
            af[m] = *(const bf16x8*)&As[(wr * 64 + m * 16 + hr) * LDSPAD + kq * 8];
        #pragma unroll
        for (int n = 0; n < 4; ++n)
            bfr[n] = *(const bf16x8*)&Bs[(wc * 64 + n * 16 + hr) * LDSPAD + kq * 8];
        #pragma unroll
        for (int m = 0; m < 4; ++m)
            #pragma unroll
            for (int n = 0; n < 4; ++n)
                acc[m][n] = __builtin_amdgcn_mfma_f32_16x16x32_bf16(af[m], bfr[n], acc[m][n], 0, 0, 0);
        __syncthreads();
    }
    float* ob = out + (size_t)b * L_ * O_;
    #pragma unroll
    for (int n = 0; n < 4; ++n) {
        const int col = nt * 128 + wc * 64 + n * 16 + hr;
        const float bv = bias[col];
        #pragma unroll
        for (int m = 0; m < 4; ++m) {
            const int row0 = mt * 128 + wr * 64 + m * 16 + kq * 4;
            #pragma unroll
            for (int j = 0; j < 4; ++j)
                ob[(size_t)(row0 + j) * O_ + col] = acc[m][n][j] + bv;
        }
    }
}

extern "C" void kernel_launch(void* const* d_in, const int* in_sizes, int n_in,
                              void* d_out, int out_size, void* d_ws, size_t ws_size,
                              hipStream_t stream) {
    const float* x       = (const float*)d_in[0];
    const float* wmean   = (const float*)d_in[1];
    const float* wlogvar = (const float*)d_in[2];
    const float* bias    = (const float*)d_in[3];
    const float* noise   = (const float*)d_in[4];
    float* out           = (float*)d_out;

    const size_t ms_bytes = (size_t)O_ * I_ * 2 * 2;   // mean bf16 + sigma bf16 = 4 MiB

    if (ws_size >= ms_bytes) {
        __bf16* mzb = (__bf16*)d_ws;
        __bf16* sgb = mzb + (size_t)O_ * I_;
        gen_ms_kernel<<<dim3(O_ * I_ / 4 / 256), dim3(256), 0, stream>>>(wmean, wlogvar, mzb, sgb);
        fused_a<<<dim3(512), dim3(512), 0, stream>>>(x, noise, mzb, sgb, bias, out);
    } else {
        bayes_gemm_fused<<<dim3(1024), dim3(256), 0, stream>>>(
            x, wmean, wlogvar, bias, noise, out);
    }
}

// Round 19
// 123.674 us; speedup vs baseline: 1.0436x; 1.0436x over previous
//
#include <hip/hip_runtime.h>
#include <hip/hip_bf16.h>
#include <stdint.h>

// Problem constants
#define B_ 32
#define L_ 512
#define I_ 1024
#define O_ 1024
#define NST 32            // K-steps of BK=32

typedef float  f32x4 __attribute__((ext_vector_type(4)));
typedef __bf16 bf16x4 __attribute__((ext_vector_type(4)));
typedef __bf16 bf16x8 __attribute__((ext_vector_type(8)));

#define CFENCE() asm volatile("" ::: "memory")
#define BARRIER() do { CFENCE(); __builtin_amdgcn_s_barrier(); CFENCE(); } while (0)
#define LGKM0()  asm volatile("s_waitcnt lgkmcnt(0)" ::: "memory")

// ---- async global->LDS, 16B per lane (zero staging registers) ----
__device__ __forceinline__ void gload_lds16(const void* g, void* l) {
    __builtin_amdgcn_global_load_lds(
        (const __attribute__((address_space(1))) uint32_t*)(uintptr_t)g,
        (__attribute__((address_space(3))) uint32_t*)(uint32_t)(uintptr_t)l,
        16, 0, 0);
}

// ============================ Pass 1: W = mean + eps * exp(0.5*lv) (bf16, 64 MiB ws) ============================
// Branchless grid-stride (R2-proven ~6 TB/s). NO cvt_x: the GEMM gloads x as raw f32
// and converts at fragment-load (R18-verified path) — saves the 96 MB xb round-trip.
__global__ void gen_w_kernel(const float* __restrict__ wmean,
                             const float* __restrict__ wlv,
                             const float* __restrict__ noise,
                             __bf16* __restrict__ W)
{
    const int n4 = B_ * O_ * I_ / 4;
    const int stride = gridDim.x * blockDim.x;
    for (int i = blockIdx.x * blockDim.x + threadIdx.x; i < n4; i += stride) {
        const int mi = i & (O_ * I_ / 4 - 1);
        const f32x4 m4 = *(const f32x4*)(wmean + (size_t)mi * 4);
        const f32x4 l4 = *(const f32x4*)(wlv   + (size_t)mi * 4);
        const f32x4 e4 = *(const f32x4*)(noise + (size_t)i  * 4);
        bf16x4 w;
        w[0] = (__bf16)(m4[0] + e4[0] * __expf(0.5f * l4[0]));
        w[1] = (__bf16)(m4[1] + e4[1] * __expf(0.5f * l4[1]));
        w[2] = (__bf16)(m4[2] + e4[2] * __expf(0.5f * l4[2]));
        w[3] = (__bf16)(m4[3] + e4[3] * __expf(0.5f * l4[3]));
        *(bf16x4*)(W + (size_t)i * 4) = w;
    }
}

// ============================ Pass 2: 128x256 GEMM, pure gload, 2 resident blocks/CU ============================
// C[b](512x1024) = X[b](f32, cvt at frag-load) * W[b]^T(bf16) + bias.
// 512 thr = 8 waves (2M x 4N), per-wave 64x64 out = 4x4 frags (acc 64 regs, NO staging regs).
// LDS 64 KB: dbuf-2 x { A f32 [128][32] 16KB (src-swizzled chunk^=(row&7), R18-verified) |
//                       B bf16 [256][32] 16KB LINEAR (read = uniform 8 lanes/bank-quad) }.
// -> 2 blocks resident per CU = 16 waves/CU: cross-block overlap covers the vmcnt/barrier
// waits that pinned every 1-block/CU gload GEMM at ~60-78us.
// Sync (R6-verified counted pattern, dbuf-2): per step {vmcnt(4) -> bar1 -> ds_read+MFMA
// -> bar2 -> STG(t+2 into buf just released)}. 4 gloads/thread/tile; vmcnt(4) = stage(t+1)
// in flight across both barriers; never drains mid-loop. Tail: vmcnt(0) at t=NST-1.
__global__ __launch_bounds__(512) void gemm_2r(const float* __restrict__ x,
                                               const __bf16* __restrict__ W,
                                               const float* __restrict__ bias,
                                               float* __restrict__ out)
{
    __shared__ __align__(16) char smem[65536];   // buf d at d*32768: A@0 (16KB), B@16384 (16KB)

    // 512 blocks, XCD swizzle (512%8==0): 64 consecutive logical blocks per XCD = 4 whole batches.
    const int bid = ((int)blockIdx.x & 7) * 64 + ((int)blockIdx.x >> 3);
    const int b   = bid >> 4;          // 16 blocks/batch
    const int mt  = (bid >> 2) & 3;    // 4 M-tiles of 128
    const int nt  = bid & 3;           // 4 N-tiles of 256

    const int tid  = threadIdx.x;      // 0..511
    const int wid  = tid >> 6, lane = tid & 63;
    const int wr   = wid >> 2;         // 0..1 (M halves of 64)
    const int wc   = wid & 3;          // 0..3 (N quarters of 64)
    const int hr   = lane & 15;
    const int kq   = lane >> 4;        // 0..3

    // ---- A staging (gload f32, R18-verified swizzle): thread owns phys chunks tid, tid+512 ----
    const int rA = tid >> 3, pcA = tid & 7;
    const int cA = pcA ^ (rA & 7);                // pre-swizzled global col chunk (4 f32 each)
    const float* xg1 = x + ((size_t)b * L_ + mt * 128 + rA) * I_ + cA * 4;
    const float* xg2 = xg1 + (size_t)64 * I_;

    // ---- B staging (gload bf16, linear): thread owns chunks tid (row tid>>2), tid+512 ----
    const int rB = tid >> 2, cB = tid & 3;
    const __bf16* wg1 = W + ((size_t)b * O_ + nt * 256 + rB) * I_ + cB * 8;
    const __bf16* wg2 = wg1 + (size_t)128 * I_;

#define STG(kt_) do {                                                   \
        char* bb_ = smem + ((kt_) & 1) * 32768;                         \
        const int ko_ = (kt_) * 32;                                     \
        gload_lds16(xg1 + ko_, bb_ + tid * 16);                         \
        gload_lds16(xg2 + ko_, bb_ + 8192 + tid * 16);                  \
        gload_lds16(wg1 + ko_, bb_ + 16384 + tid * 16);                 \
        gload_lds16(wg2 + ko_, bb_ + 16384 + 8192 + tid * 16);          \
    } while (0)

    // ---- frag read offsets ----
    // A (f32 rows of 128B): row = wr*64 + f*16 + hr; chunks (kq*2+j) ^ (hr&7)  [R18-verified]
    int aoff[4][2];
    #pragma unroll
    for (int f = 0; f < 4; ++f)
        #pragma unroll
        for (int j = 0; j < 2; ++j)
            aoff[f][j] = (wr * 64 + f * 16 + hr) * 128 + (((kq * 2 + j) ^ (hr & 7)) * 16);
    // B (bf16 rows of 64B, linear): row = wc*64 + n*16 + hr; chunk kq -> quad kq+4*(hr&1), uniform
    int boff[4];
    #pragma unroll
    for (int n = 0; n < 4; ++n)
        boff[n] = 16384 + (wc * 64 + n * 16 + hr) * 64 + kq * 16;

    f32x4 acc[4][4];
    #pragma unroll
    for (int m = 0; m < 4; ++m)
        #pragma unroll
        for (int n = 0; n < 4; ++n)
            acc[m][n] = (f32x4)(0.0f);

    // ---- prologue: stages 0 and 1 in flight (8 loads) ----
    STG(0);
    STG(1);

    for (int t = 0; t < NST; ++t) {
        // counted wait: stage t complete; stage t+1 (4 loads) stays in flight
        if (t + 1 < NST) { CFENCE(); asm volatile("s_waitcnt vmcnt(4)" ::: "memory"); }
        else             { CFENCE(); asm volatile("s_waitcnt vmcnt(0)" ::: "memory"); }
        BARRIER();

        const char* base = smem + (t & 1) * 32768;
        bf16x8 af[4], bfr[4];
        #pragma unroll
        for (int f = 0; f < 4; ++f) {
            const f32x4 lo = *(const f32x4*)(base + aoff[f][0]);
            const f32x4 hi = *(const f32x4*)(base + aoff[f][1]);
            bf16x8 a_;
            #pragma unroll
            for (int e = 0; e < 4; ++e) { a_[e] = (__bf16)lo[e]; a_[e+4] = (__bf16)hi[e]; }
            af[f] = a_;
        }
        #pragma unroll
        for (int n = 0; n < 4; ++n)
            bfr[n] = *(const bf16x8*)(base + boff[n]);

        __builtin_amdgcn_s_setprio(1);
        #pragma unroll
        for (int m = 0; m < 4; ++m)
            #pragma unroll
            for (int n = 0; n < 4; ++n)
                acc[m][n] = __builtin_amdgcn_mfma_f32_16x16x32_bf16(af[m], bfr[n], acc[m][n], 0, 0, 0);
        __builtin_amdgcn_s_setprio(0);

        BARRIER();                      // all waves done reading buf (t&1)
        if (t + 2 < NST) STG(t + 2);    // refill the just-released buffer; rides into next step
    }
#undef STG

    // ---- epilogue (R18-verified): LDS transpose -> coalesced 1KB-row stores; 4 rounds x 32 rows ----
    {
        float* eb = (float*)smem;                  // [32][260] f32 = 33.3 KB
        const f32x4 bias4 = *(const f32x4*)(bias + nt * 256 + lane * 4);
        float* ob = out + ((size_t)b * L_ + mt * 128) * O_ + nt * 256;
        #pragma unroll
        for (int r = 0; r < 4; ++r) {
            BARRIER();                             // prior LDS use done
            if (wr == (r >> 1)) {
                #pragma unroll
                for (int m2 = 0; m2 < 2; ++m2) {
                    const int mf = (r & 1) * 2 + m2;
                    #pragma unroll
                    for (int n = 0; n < 4; ++n) {
                        const int col = wc * 64 + n * 16 + hr;
                        #pragma unroll
                        for (int j = 0; j < 4; ++j)
                            eb[(m2 * 16 + kq * 4 + j) * 260 + col] = acc[mf][n][j];
                    }
                }
            }
            LGKM0();
            BARRIER();                             // publish slab
            #pragma unroll
            for (int rr = 0; rr < 4; ++rr) {
                const int row = wid * 4 + rr;      // 0..31
                f32x4 v = *(const f32x4*)&eb[row * 260 + lane * 4];
                v += bias4;
                *(f32x4*)&ob[(size_t)(r * 32 + row) * O_ + lane * 4] = v;
            }
        }
    }
}

// ============================ Fallback (no workspace): R1 fused kernel ============================
#define LDSPAD 40
__global__ void bayes_gemm_fused(const float* __restrict__ x,
                                 const float* __restrict__ wmean,
                                 const float* __restrict__ wlogvar,
                                 const float* __restrict__ bias,
                                 const float* __restrict__ noise,
                                 float* __restrict__ out)
{
    __shared__ __bf16 As[128 * LDSPAD];
    __shared__ __bf16 Bs[128 * LDSPAD];
    const int bid  = blockIdx.x;
    const int b    = bid >> 5;
    const int mt   = (bid >> 3) & 3;
    const int nt   = bid & 7;
    const int t    = threadIdx.x;
    const int wave = t >> 6, lane = t & 63;
    const int wr   = wave >> 1, wc = wave & 1;
    const int hr   = lane & 15, kq = lane >> 4;
    const float* xb = x     + (size_t)b * L_ * I_;
    const float* nb = noise + (size_t)b * O_ * I_;
    f32x4 acc[4][4];
    #pragma unroll
    for (int m = 0; m < 4; ++m)
        #pragma unroll
        for (int n = 0; n < 4; ++n) acc[m][n] = (f32x4)(0.0f);
    for (int k0 = 0; k0 < I_; k0 += 32) {
        #pragma unroll
        for (int j = 0; j < 4; ++j) {
            const int s = t + j * 256, row = s >> 3, q = s & 7;
            const float4 v = *(const float4*)(xb + (size_t)(mt * 128 + row) * I_ + k0 + q * 4);
            __bf16* dst = &As[row * LDSPAD + q * 4];
            dst[0] = (__bf16)v.x; dst[1] = (__bf16)v.y; dst[2] = (__bf16)v.z; dst[3] = (__bf16)v.w;
        }
        #pragma unroll
        for (int j = 0; j < 4; ++j) {
            const int s = t + j * 256, row = s >> 3, q = s & 7;
            const size_t off = (size_t)(nt * 128 + row) * I_ + k0 + q * 4;
            const float4 m4 = *(const float4*)(wmean + off);
            const float4 l4 = *(const float4*)(wlogvar + off);
            const float4 n4 = *(const float4*)(nb + off);
            __bf16* dst = &Bs[row * LDSPAD + q * 4];
            dst[0] = (__bf16)(m4.x + n4.x * __expf(0.5f * l4.x));
            dst[1] = (__bf16)(m4.y + n4.y * __expf(0.5f * l4.y));
            dst[2] = (__bf16)(m4.z + n4.z * __expf(0.5f * l4.z));
            dst[3] = (__bf16)(m4.w + n4.w * __expf(0.5f * l4.w));
        }
        __syncthreads();
        bf16x8 af[4], bfr[4];
        #pragma unroll
        for (int m = 0; m < 4; ++m)
            af[m] = *(const bf16x8*)&As[(wr * 64 + m * 16 + hr) * LDSPAD + kq * 8];
        #pragma unroll
        for (int n = 0; n < 4; ++n)
            bfr[n] = *(const bf16x8*)&Bs[(wc * 64 + n * 16 + hr) * LDSPAD + kq * 8];
        #pragma unroll
        for (int m = 0; m < 4; ++m)
            #pragma unroll
            for (int n = 0; n < 4; ++n)
                acc[m][n] = __builtin_amdgcn_mfma_f32_16x16x32_bf16(af[m], bfr[n], acc[m][n], 0, 0, 0);
        __syncthreads();
    }
    float* ob = out + (size_t)b * L_ * O_;
    #pragma unroll
    for (int n = 0; n < 4; ++n) {
        const int col = nt * 128 + wc * 64 + n * 16 + hr;
        const float bv = bias[col];
        #pragma unroll
        for (int m = 0; m < 4; ++m) {
            const int row0 = mt * 128 + wr * 64 + m * 16 + kq * 4;
            #pragma unroll
            for (int j = 0; j < 4; ++j)
                ob[(size_t)(row0 + j) * O_ + col] = acc[m][n][j] + bv;
        }
    }
}

extern "C" void kernel_launch(void* const* d_in, const int* in_sizes, int n_in,
                              void* d_out, int out_size, void* d_ws, size_t ws_size,
                              hipStream_t stream) {
    const float* x       = (const float*)d_in[0];
    const float* wmean   = (const float*)d_in[1];
    const float* wlogvar = (const float*)d_in[2];
    const float* bias    = (const float*)d_in[3];
    const float* noise   = (const float*)d_in[4];
    float* out           = (float*)d_out;

    const size_t w_bytes = (size_t)B_ * O_ * I_ * 2;   // 64 MiB

    if (ws_size >= w_bytes) {
        __bf16* W = (__bf16*)d_ws;
        gen_w_kernel<<<dim3(2048), dim3(256), 0, stream>>>(wmean, wlogvar, noise, W);
        gemm_2r<<<dim3(512), dim3(512), 0, stream>>>(x, W, bias, out);
    } else {
        bayes_gemm_fused<<<dim3(1024), dim3(256), 0, stream>>>(
            x, wmean, wlogvar, bias, noise, out);
    }
}